// Round 6
// baseline (3175.538 us; speedup 1.0000x reference)
//
#include <hip/hip_runtime.h>
#include <hip/hip_bf16.h>

#define N_NODES 10000
#define N_EDGES 160000

typedef short v8s __attribute__((ext_vector_type(8)));
typedef float v4f __attribute__((ext_vector_type(4)));

__device__ __forceinline__ float bf2f(ushort u) {
    union { unsigned i; float f; } x; x.i = ((unsigned)u) << 16; return x.f;
}
// NaN -> 0, clamp to finite: keeps residual bugs finite/diagnosable.
__device__ __forceinline__ float fin(float x) {
    return (x == x) ? fminf(fmaxf(x, -1e30f), 1e30f) : 0.f;
}
__device__ __forceinline__ ushort f2bf(float f) {
    union { unsigned i; float f; } x; x.f = fin(f);
    unsigned i = x.i;
    unsigned r = (i + 0x7fffu + ((i >> 16) & 1u)) >> 16;
    return (ushort)r;
}

#define INV_C 0.08838834764831845f      /* 1/sqrt(128) */
#define S_MLP1 0.08574929257125442f     /* 1/sqrt(136) */
#define S_MLP 0.0625f                   /* 1/16 */
#define INV_SQRT3 0.5773502691896258f
#define OUT_SCALE 0.00390625f           /* (1/sqrt(256))/16 */

// ---------------------------------------------------------------------------
// Weight pre-pack: fp32 weights -> bf16 MFMA B-fragment order.
// B-frag (16x16x32): lane l holds B[k = kt*32 + (l>>4)*8 + j][n = nt*16 + (l&15)]
// packed flat index: ((nt*KT + kt)*64 + l)*8 + j
// ---------------------------------------------------------------------------
__global__ __launch_bounds__(256) void pack_kernel(
    const float* __restrict__ w1, const float* __restrict__ w2,
    const float* __restrict__ w3, const float* __restrict__ w4,
    ushort* __restrict__ w1p, ushort* __restrict__ w2p,
    ushort* __restrict__ w3p, ushort* __restrict__ w4p)
{
    int idx = blockIdx.x * 256 + threadIdx.x;
    const float* W; ushort* D; int KT, Kreal, Nn, id;
    if (idx < 40960)       { W = w1; D = w1p; KT = 5; Kreal = 136; Nn = 256; id = idx; }
    else if (idx < 106496) { W = w2; D = w2p; KT = 8; Kreal = 256; Nn = 256; id = idx - 40960; }
    else if (idx < 172032) { W = w3; D = w3p; KT = 8; Kreal = 256; Nn = 256; id = idx - 106496; }
    else                   { W = w4; D = w4p; KT = 8; Kreal = 256; Nn = 512; id = idx - 172032; }
    int j = id & 7, lane = (id >> 3) & 63, tt = id >> 9;
    int kt = tt % KT, nt = tt / KT;
    int k = kt * 32 + ((lane >> 4) << 3) + j;
    int nn = nt * 16 + (lane & 15);
    D[id] = (k < Kreal) ? f2bf(W[k * Nn + nn]) : (ushort)0;
}

// ---------------------------------------------------------------------------
// Node up/down projections (fp32 in): u0, u1, down -> bf16 scratch.
// ---------------------------------------------------------------------------
__global__ __launch_bounds__(256) void node_uud_kernel(
    const float* __restrict__ nf,
    const float* __restrict__ Wu0, const float* __restrict__ Wu1,
    const float* __restrict__ Wd,
    ushort* __restrict__ u0, ushort* __restrict__ u1,
    ushort* __restrict__ down)
{
    __shared__ float x[512];
    int n = blockIdx.x, t = threadIdx.x;
    for (int i = t; i < 512; i += 256) x[i] = nf[(size_t)n * 512 + i];
    __syncthreads();
    int v = t & 127;
    if (t < 128) {
        float acc = 0.f;
        for (int u = 0; u < 128; ++u) acc += x[u] * Wu0[u * 128 + v];
        u0[(size_t)n * 128 + v] = f2bf(acc * INV_C);
        if (t < 64) {
            float a3 = 0.f;
            for (int u = 0; u < 128; ++u) a3 += x[u] * Wd[u * 64 + t];
            down[(size_t)n * 64 + t] = f2bf(a3 * INV_C);
        }
    } else {
        for (int i = 0; i < 3; ++i) {
            float a2 = 0.f;
            for (int u = 0; u < 128; ++u) a2 += x[128 + u * 3 + i] * Wu1[u * 128 + v];
            u1[(size_t)n * 384 + v * 3 + i] = f2bf(a2 * INV_C);
        }
    }
}

// ---------------------------------------------------------------------------
// Skip connection (runs LAST — overwrites scratch with fp32 sc output).
// fp32 in, fp32 accumulate, fp32 out: near-exact.
// ---------------------------------------------------------------------------
__global__ __launch_bounds__(256) void node_sc_kernel(
    const float* __restrict__ nf,
    const float* __restrict__ Ws0, const float* __restrict__ Ws1,
    float* __restrict__ out_sc)
{
    __shared__ float x[512];
    int n = blockIdx.x, t = threadIdx.x;
    for (int i = t; i < 512; i += 256) x[i] = nf[(size_t)n * 512 + i];
    __syncthreads();
    int v = t & 127;
    if (t < 128) {
        float acc = 0.f;
        for (int u = 0; u < 128; ++u) acc += x[u] * Ws0[u * 128 + v];
        out_sc[(size_t)n * 512 + v] = fin(acc * INV_C);
    } else {
        for (int i = 0; i < 3; ++i) {
            float a2 = 0.f;
            for (int u = 0; u < 128; ++u) a2 += x[128 + u * 3 + i] * Ws1[u * 128 + v];
            out_sc[(size_t)n * 512 + 128 + v * 3 + i] = fin(a2 * INV_C);
        }
    }
}

// ---------------------------------------------------------------------------
// CSR build
// ---------------------------------------------------------------------------
__global__ __launch_bounds__(256) void hist_kernel(const int* __restrict__ eidx, int* __restrict__ counts)
{
    int e = blockIdx.x * 256 + threadIdx.x;
    int r = eidx[N_EDGES + e];
    if (r < 0) r = 0; if (r >= N_NODES) r = N_NODES - 1;
    atomicAdd(&counts[r], 1);
}

__global__ __launch_bounds__(1024) void scan_kernel(const int* __restrict__ counts, int* __restrict__ offs)
{
    __shared__ int buf[1024];
    __shared__ int base_s;
    int t = threadIdx.x;
    if (t == 0) { base_s = 0; offs[0] = 0; }
    __syncthreads();
    for (int chunk = 0; chunk < (N_NODES + 1023) / 1024; ++chunk) {
        int i = chunk * 1024 + t;
        int vv = (i < N_NODES) ? counts[i] : 0;
        buf[t] = vv;
        __syncthreads();
        for (int off = 1; off < 1024; off <<= 1) {
            int xv = (t >= off) ? buf[t - off] : 0;
            __syncthreads();
            buf[t] += xv;
            __syncthreads();
        }
        int incl = buf[t];
        int base = base_s;
        __syncthreads();
        if (i < N_NODES) offs[i + 1] = base + incl;
        if (t == 1023) base_s = base + incl;
        __syncthreads();
    }
}

__global__ __launch_bounds__(256) void fill_kernel(
    const int* __restrict__ eidx, const int* __restrict__ offs,
    int* __restrict__ cnt2, int* __restrict__ esort)
{
    int e = blockIdx.x * 256 + threadIdx.x;
    int r = eidx[N_EDGES + e];
    if (r < 0) r = 0; if (r >= N_NODES) r = N_NODES - 1;
    int k = atomicAdd(&cnt2[r], 1);
    int pos = offs[r] + k;
    if (pos < 0) pos = 0; if (pos >= N_EDGES) pos = N_EDGES - 1;
    esort[pos] = e;
}

// ---------------------------------------------------------------------------
// MFMA GEMM layer (hidden layers): 32 edges x 256 out, bf16 LDS->LDS.
// A-frag: lane l holds A[m=l&15][k=(l>>4)*8+j]; C/D: row=(l>>4)*4+r, col=l&15.
// ---------------------------------------------------------------------------
#define H_STRIDE 264

template <int KT, bool SILU>
__device__ __forceinline__ void gemm_layer(
    const ushort* __restrict__ wpack, const ushort* srcLDS, int srcStride,
    ushort* dstLDS, float scale)
{
    int t = threadIdx.x;
    int w = t >> 6, l = t & 63;
    int mt = w & 1;
    int ntbase = (w >> 1) * 8;
    int lrow = l & 15, q = l >> 4;

    v8s a[KT];
#pragma unroll
    for (int kt = 0; kt < KT; ++kt)
        a[kt] = *(const v8s*)&srcLDS[(mt * 16 + lrow) * srcStride + kt * 32 + q * 8];

    for (int p = 0; p < 4; ++p) {
        int nt0 = ntbase + 2 * p, nt1 = nt0 + 1;
        v4f acc0 = {0.f, 0.f, 0.f, 0.f}, acc1 = {0.f, 0.f, 0.f, 0.f};
#pragma unroll
        for (int kt = 0; kt < KT; ++kt) {
            v8s b0 = *(const v8s*)&wpack[(size_t)(nt0 * KT + kt) * 512 + l * 8];
            v8s b1 = *(const v8s*)&wpack[(size_t)(nt1 * KT + kt) * 512 + l * 8];
            acc0 = __builtin_amdgcn_mfma_f32_16x16x32_bf16(a[kt], b0, acc0, 0, 0, 0);
            acc1 = __builtin_amdgcn_mfma_f32_16x16x32_bf16(a[kt], b1, acc1, 0, 0, 0);
        }
#pragma unroll
        for (int r = 0; r < 4; ++r) {
            float x0 = acc0[r] * scale, x1 = acc1[r] * scale;
            if (SILU) {
                x0 = x0 / (1.f + __expf(-x0));
                x1 = x1 / (1.f + __expf(-x1));
            }
            int row = mt * 16 + q * 4 + r;
            dstLDS[row * H_STRIDE + nt0 * 16 + lrow] = f2bf(x0);
            dstLDS[row * H_STRIDE + nt1 * 16 + lrow] = f2bf(x1);
        }
    }
    __syncthreads();
}

// ---------------------------------------------------------------------------
// Fused per-node kernel: one block per receiver node. Per 32-edge CSR chunk:
// stage aug, 3 hidden GEMM layers, then layer 4 quarter-by-quarter (fp32 LDS)
// contracted into per-thread register accumulators. Epilogue applies W_lin.
// Writes fp32 message.
// ---------------------------------------------------------------------------
__global__ __launch_bounds__(256) void node_msg_kernel(
    const int* __restrict__ offs, const int* __restrict__ esort,
    const int* __restrict__ eidx,
    const float* __restrict__ ef, const float* __restrict__ ea,
    const ushort* __restrict__ down,
    const ushort* __restrict__ u0, const ushort* __restrict__ u1,
    const ushort* __restrict__ w1p, const ushort* __restrict__ w2p,
    const ushort* __restrict__ w3p, const ushort* __restrict__ w4p,
    const float* __restrict__ WL0, const float* __restrict__ WL1,
    float* __restrict__ out_msg)
{
    __shared__ __align__(16) ushort s_aug[32 * 168];
    __shared__ __align__(16) ushort s_h[2][32 * H_STRIDE];
    __shared__ __align__(16) float s_q[32 * 132];
    __shared__ float s_m[1024];
    __shared__ int s_e[32];
    __shared__ int s_s[32];
    __shared__ float s_y[32][4];

    int n = blockIdx.x, t = threadIdx.x;
    int beg = offs[n];
    if (beg < 0) beg = 0; if (beg > N_EDGES) beg = N_EDGES;
    int end = offs[n + 1];
    if (end < beg) end = beg; if (end > N_EDGES) end = N_EDGES;
    int deg = end - beg;

    float am0 = 0.f, am1a = 0.f, am1b = 0.f, am1c = 0.f;
    int c = t & 127;
    int w = t >> 6, l = t & 63;
    int mt = w & 1;
    int lrow = l & 15, q = l >> 4;

    for (int chunk = 0; chunk * 32 < deg; ++chunk) {
        int ecnt = deg - chunk * 32; if (ecnt > 32) ecnt = 32;
        __syncthreads();
        if (t < 32) {
            int sv = 0, e = 0;
            if (t < ecnt) {
                e = esort[beg + chunk * 32 + t];
                if (e < 0) e = 0; if (e >= N_EDGES) e = N_EDGES - 1;
                sv = eidx[e];
                if (sv < 0) sv = 0; if (sv >= N_NODES) sv = N_NODES - 1;
                s_y[t][0] = fin(ea[(size_t)e * 4 + 0]);
                s_y[t][1] = fin(ea[(size_t)e * 4 + 1]);
                s_y[t][2] = fin(ea[(size_t)e * 4 + 2]);
                s_y[t][3] = fin(ea[(size_t)e * 4 + 3]);
            } else {
                s_y[t][0] = 0.f; s_y[t][1] = 0.f; s_y[t][2] = 0.f; s_y[t][3] = 0.f;
            }
            s_e[t] = e;
            s_s[t] = sv;
        }
        __syncthreads();
        // aug = [edge_feats(8) | down[sender](64) | down[receiver=n](64) | 0-pad]
        for (int i = t; i < 32 * 168; i += 256) {
            int e = i / 168, cc = i - e * 168;
            ushort vv = 0;
            if (e < ecnt) {
                if (cc < 8)        vv = f2bf(ef[(size_t)s_e[e] * 8 + cc]);
                else if (cc < 72)  vv = down[(size_t)s_s[e] * 64 + (cc - 8)];
                else if (cc < 136) vv = down[(size_t)n * 64 + (cc - 72)];
            }
            s_aug[i] = vv;
        }
        __syncthreads();
        gemm_layer<5, true>(w1p, s_aug, 168, s_h[0], S_MLP1);
        gemm_layer<8, true>(w2p, s_h[0], H_STRIDE, s_h[1], S_MLP);
        gemm_layer<8, true>(w3p, s_h[1], H_STRIDE, s_h[0], S_MLP);

        // ---- layer 4, quarter-by-quarter (w0|w1|w2|w3 = 128 cols each) ----
        v8s a4[8];
#pragma unroll
        for (int kt = 0; kt < 8; ++kt)
            a4[kt] = *(const v8s*)&s_h[0][(mt * 16 + lrow) * H_STRIDE + kt * 32 + q * 8];

        for (int qd = 0; qd < 4; ++qd) {
#pragma unroll
            for (int pp = 0; pp < 2; ++pp) {
                int nt0 = qd * 8 + (w >> 1) * 4 + pp * 2;
                int nt1 = nt0 + 1;
                v4f acc0 = {0.f, 0.f, 0.f, 0.f}, acc1 = {0.f, 0.f, 0.f, 0.f};
#pragma unroll
                for (int kt = 0; kt < 8; ++kt) {
                    v8s b0 = *(const v8s*)&w4p[(size_t)(nt0 * 8 + kt) * 512 + l * 8];
                    v8s b1 = *(const v8s*)&w4p[(size_t)(nt1 * 8 + kt) * 512 + l * 8];
                    acc0 = __builtin_amdgcn_mfma_f32_16x16x32_bf16(a4[kt], b0, acc0, 0, 0, 0);
                    acc1 = __builtin_amdgcn_mfma_f32_16x16x32_bf16(a4[kt], b1, acc1, 0, 0, 0);
                }
                int col0 = (nt0 * 16 + lrow) & 127;
                int col1 = col0 + 16;
#pragma unroll
                for (int r = 0; r < 4; ++r) {
                    int row = mt * 16 + q * 4 + r;
                    s_q[row * 132 + col0] = acc0[r] * S_MLP;
                    s_q[row * 132 + col1] = acc1[r] * S_MLP;
                }
            }
            __syncthreads();
            if (qd == 0 && t < 128) {            // w0 -> m0[c] (o0a)
                for (int e = 0; e < ecnt; ++e)
                    am0 += s_q[e * 132 + c] * bf2f(u0[(size_t)s_s[e] * 128 + c]) * s_y[e][0];
            } else if (qd == 1 && t < 128) {     // w1 -> m1 rows c (o1a)
                for (int e = 0; e < ecnt; ++e) {
                    float wx = s_q[e * 132 + c] * bf2f(u0[(size_t)s_s[e] * 128 + c]);
                    am1a += wx * s_y[e][1]; am1b += wx * s_y[e][2]; am1c += wx * s_y[e][3];
                }
            } else if (qd == 2 && t >= 128) {    // w2 -> m1 rows 128+c (o1b)
                for (int e = 0; e < ecnt; ++e) {
                    float w2v = s_q[e * 132 + c] * s_y[e][0];
                    size_t ub = (size_t)s_s[e] * 384 + c * 3;
                    am1a += w2v * bf2f(u1[ub]);
                    am1b += w2v * bf2f(u1[ub + 1]);
                    am1c += w2v * bf2f(u1[ub + 2]);
                }
            } else if (qd == 3 && t >= 128) {    // w3 -> m0[128+c] (o0b)
                for (int e = 0; e < ecnt; ++e) {
                    size_t ub = (size_t)s_s[e] * 384 + c * 3;
                    float d = bf2f(u1[ub])     * s_y[e][1]
                            + bf2f(u1[ub + 1]) * s_y[e][2]
                            + bf2f(u1[ub + 2]) * s_y[e][3];
                    am0 += s_q[e * 132 + c] * d;
                }
            }
            __syncthreads();
        }
    }

    // ---- epilogue: m -> LDS, apply W_lin0 / W_lin1, fp32 out ----
    __syncthreads();
    if (t < 128) {
        s_m[c] = am0;
        s_m[256 + c * 3 + 0] = am1a;
        s_m[256 + c * 3 + 1] = am1b;
        s_m[256 + c * 3 + 2] = am1c;
    } else {
        s_m[128 + c] = am0 * INV_SQRT3;
        s_m[256 + (128 + c) * 3 + 0] = am1a;
        s_m[256 + (128 + c) * 3 + 1] = am1b;
        s_m[256 + (128 + c) * 3 + 2] = am1c;
    }
    __syncthreads();
    if (t < 128) {
        float s2 = 0.f;
        for (int u = 0; u < 256; ++u) s2 += s_m[u] * WL0[u * 128 + t];
        out_msg[(size_t)n * 512 + t * 4 + 0] = fin(s2 * OUT_SCALE);
    } else {
        float s0 = 0.f, s1 = 0.f, s2 = 0.f;
        for (int u = 0; u < 256; ++u) {
            float wv = WL1[u * 128 + c];
            s0 += s_m[256 + u * 3 + 0] * wv;
            s1 += s_m[256 + u * 3 + 1] * wv;
            s2 += s_m[256 + u * 3 + 2] * wv;
        }
        out_msg[(size_t)n * 512 + c * 4 + 1] = fin(s0 * OUT_SCALE);
        out_msg[(size_t)n * 512 + c * 4 + 2] = fin(s1 * OUT_SCALE);
        out_msg[(size_t)n * 512 + c * 4 + 3] = fin(s2 * OUT_SCALE);
    }
}

// ---------------------------------------------------------------------------
extern "C" void kernel_launch(void* const* d_in, const int* in_sizes, int n_in,
                              void* d_out, int out_size, void* d_ws, size_t ws_size,
                              hipStream_t stream)
{
    (void)d_ws; (void)ws_size;   // d_ws unused (size unknown)

    // Inputs fp32 (edge_index int32). OUTPUT IS FP32 (reference output dtype).
    const float* node_feats = (const float*)d_in[1];
    const float* edge_attrs = (const float*)d_in[2];
    const float* edge_feats = (const float*)d_in[3];
    const int*   edge_index = (const int*)d_in[4];
    const float* W_up0  = (const float*)d_in[5];
    const float* W_up1  = (const float*)d_in[6];
    const float* W_down = (const float*)d_in[7];
    const float* mlp_w1 = (const float*)d_in[8];
    const float* mlp_w2 = (const float*)d_in[9];
    const float* mlp_w3 = (const float*)d_in[10];
    const float* mlp_w4 = (const float*)d_in[11];
    const float* W_lin0 = (const float*)d_in[12];
    const float* W_lin1 = (const float*)d_in[13];
    const float* W_skip0 = (const float*)d_in[14];
    const float* W_skip1 = (const float*)d_in[15];

    // d_out fp32: [message: N*512 = 20,480,000 B][sc: N*512 = 20,480,000 B]
    char* M = (char*)d_out;                 // message half (counts/cnt2 early)
    char* S = (char*)d_out + 20480000;      // sc half (scratch until node_sc)

    // Scratch inside S (total 12,806,240 B < 20,480,000 B):
    ushort* u0    = (ushort*)(S + 0);           //  2,560,000 B
    ushort* down  = (ushort*)(S + 2560000);     //  1,280,000 B
    ushort* u1    = (ushort*)(S + 3840000);     //  7,680,000 B
    ushort* w1p   = (ushort*)(S + 11520000);    //     81,920 B
    ushort* w2p   = (ushort*)(S + 11601920);    //    131,072 B
    ushort* w3p   = (ushort*)(S + 11732992);    //    131,072 B
    ushort* w4p   = (ushort*)(S + 11864064);    //    262,144 B
    int*    offs  = (int*)(S + 12126208);       //     40,032 B
    int*    esort = (int*)(S + 12166240);       //    640,000 B -> 12,806,240
    // Scratch in M (dead before node_msg writes messages):
    int*    counts = (int*)(M + 0);             //     40,000 B
    int*    cnt2   = (int*)(M + 40000);         //     40,000 B

    float* out_msg = (float*)d_out;
    float* out_sc  = (float*)d_out + (size_t)N_NODES * 512;

    hipMemsetAsync(counts, 0, 80000, stream);

    pack_kernel<<<1184, 256, 0, stream>>>(mlp_w1, mlp_w2, mlp_w3, mlp_w4, w1p, w2p, w3p, w4p);
    node_uud_kernel<<<N_NODES, 256, 0, stream>>>(node_feats, W_up0, W_up1, W_down, u0, u1, down);
    hist_kernel<<<N_EDGES / 256, 256, 0, stream>>>(edge_index, counts);
    scan_kernel<<<1, 1024, 0, stream>>>(counts, offs);
    fill_kernel<<<N_EDGES / 256, 256, 0, stream>>>(edge_index, offs, cnt2, esort);
    node_msg_kernel<<<N_NODES, 256, 0, stream>>>(offs, esort, edge_index,
                                                 edge_feats, edge_attrs, down, u0, u1,
                                                 w1p, w2p, w3p, w4p, W_lin0, W_lin1, out_msg);
    node_sc_kernel<<<N_NODES, 256, 0, stream>>>(node_feats, W_skip0, W_skip1, out_sc);
}

// Round 7
// 1449.134 us; speedup vs baseline: 2.1913x; 2.1913x over previous
//
#include <hip/hip_runtime.h>
#include <hip/hip_bf16.h>

#define N_NODES 10000
#define N_EDGES 160000

typedef short v8s __attribute__((ext_vector_type(8)));
typedef float v4f __attribute__((ext_vector_type(4)));

__device__ __forceinline__ float bf2f(ushort u) {
    union { unsigned i; float f; } x; x.i = ((unsigned)u) << 16; return x.f;
}
__device__ __forceinline__ float fin(float x) {
    return (x == x) ? fminf(fmaxf(x, -1e30f), 1e30f) : 0.f;
}
__device__ __forceinline__ ushort f2bf(float f) {
    union { unsigned i; float f; } x; x.f = fin(f);
    unsigned i = x.i;
    unsigned r = (i + 0x7fffu + ((i >> 16) & 1u)) >> 16;
    return (ushort)r;
}

#define INV_C 0.08838834764831845f      /* 1/sqrt(128) */
#define S_MLP1 0.08574929257125442f     /* 1/sqrt(136) */
#define S_MLP 0.0625f                   /* 1/16 */
#define INV_SQRT3 0.5773502691896258f
#define OUT_SCALE 0.00390625f           /* (1/sqrt(256))/16 */

// ---------------------------------------------------------------------------
// Weight pre-pack: fp32 -> bf16 MFMA B-fragment order.
// B-frag (16x16x32): lane l holds B[k = kt*32 + (l>>4)*8 + j][n = nt*16 + (l&15)]
// packed flat index: ((nt*KT + kt)*64 + l)*8 + j
// ---------------------------------------------------------------------------
__global__ __launch_bounds__(256) void pack_kernel(
    const float* __restrict__ w1, const float* __restrict__ w2,
    const float* __restrict__ w3, const float* __restrict__ w4,
    const float* __restrict__ wl0, const float* __restrict__ wl1,
    ushort* __restrict__ w1p, ushort* __restrict__ w2p,
    ushort* __restrict__ w3p, ushort* __restrict__ w4p,
    ushort* __restrict__ wl0p, ushort* __restrict__ wl1p)
{
    int idx = blockIdx.x * 256 + threadIdx.x;
    const float* W; ushort* D; int KT, Kreal, Nn, id;
    if (idx < 40960)       { W = w1;  D = w1p;  KT = 5; Kreal = 136; Nn = 256; id = idx; }
    else if (idx < 106496) { W = w2;  D = w2p;  KT = 8; Kreal = 256; Nn = 256; id = idx - 40960; }
    else if (idx < 172032) { W = w3;  D = w3p;  KT = 8; Kreal = 256; Nn = 256; id = idx - 106496; }
    else if (idx < 303104) { W = w4;  D = w4p;  KT = 8; Kreal = 256; Nn = 512; id = idx - 172032; }
    else if (idx < 335872) { W = wl0; D = wl0p; KT = 8; Kreal = 256; Nn = 128; id = idx - 303104; }
    else                   { W = wl1; D = wl1p; KT = 8; Kreal = 256; Nn = 128; id = idx - 335872; }
    int j = id & 7, lane = (id >> 3) & 63, tt = id >> 9;
    int kt = tt % KT, nt = tt / KT;
    int k = kt * 32 + ((lane >> 4) << 3) + j;
    int nn = nt * 16 + (lane & 15);
    D[id] = (k < Kreal) ? f2bf(W[k * Nn + nn]) : (ushort)0;
}

// ---------------------------------------------------------------------------
// Node up/down projections (fp32 in): u0, u1, down -> bf16 scratch.
// ---------------------------------------------------------------------------
__global__ __launch_bounds__(256) void node_uud_kernel(
    const float* __restrict__ nf,
    const float* __restrict__ Wu0, const float* __restrict__ Wu1,
    const float* __restrict__ Wd,
    ushort* __restrict__ u0, ushort* __restrict__ u1,
    ushort* __restrict__ down)
{
    __shared__ float x[512];
    int n = blockIdx.x, t = threadIdx.x;
    for (int i = t; i < 512; i += 256) x[i] = nf[(size_t)n * 512 + i];
    __syncthreads();
    int v = t & 127;
    if (t < 128) {
        float acc = 0.f;
        for (int u = 0; u < 128; ++u) acc += x[u] * Wu0[u * 128 + v];
        u0[(size_t)n * 128 + v] = f2bf(acc * INV_C);
        if (t < 64) {
            float a3 = 0.f;
            for (int u = 0; u < 128; ++u) a3 += x[u] * Wd[u * 64 + t];
            down[(size_t)n * 64 + t] = f2bf(a3 * INV_C);
        }
    } else {
        for (int i = 0; i < 3; ++i) {
            float a2 = 0.f;
            for (int u = 0; u < 128; ++u) a2 += x[128 + u * 3 + i] * Wu1[u * 128 + v];
            u1[(size_t)n * 384 + v * 3 + i] = f2bf(a2 * INV_C);
        }
    }
}

// ---------------------------------------------------------------------------
// Skip connection (runs LAST — overwrites scratch with fp32 sc output).
// ---------------------------------------------------------------------------
__global__ __launch_bounds__(256) void node_sc_kernel(
    const float* __restrict__ nf,
    const float* __restrict__ Ws0, const float* __restrict__ Ws1,
    float* __restrict__ out_sc)
{
    __shared__ float x[512];
    int n = blockIdx.x, t = threadIdx.x;
    for (int i = t; i < 512; i += 256) x[i] = nf[(size_t)n * 512 + i];
    __syncthreads();
    int v = t & 127;
    if (t < 128) {
        float acc = 0.f;
        for (int u = 0; u < 128; ++u) acc += x[u] * Ws0[u * 128 + v];
        out_sc[(size_t)n * 512 + v] = fin(acc * INV_C);
    } else {
        for (int i = 0; i < 3; ++i) {
            float a2 = 0.f;
            for (int u = 0; u < 128; ++u) a2 += x[128 + u * 3 + i] * Ws1[u * 128 + v];
            out_sc[(size_t)n * 512 + 128 + v * 3 + i] = fin(a2 * INV_C);
        }
    }
}

// ---------------------------------------------------------------------------
// Hidden-layer MFMA GEMM: 32 edges x 256 out, bf16 LDS->LDS.
// A-frag: lane l holds A[m=l&15][k=(l>>4)*8+j]; C/D: row=(l>>4)*4+r, col=l&15.
// ---------------------------------------------------------------------------
#define H_STRIDE 264

template <int KT, bool SILU>
__device__ __forceinline__ void gemm_layer(
    const ushort* __restrict__ wpack, const ushort* srcLDS, int srcStride,
    ushort* dstLDS, float scale)
{
    int t = threadIdx.x;
    int w = t >> 6, l = t & 63;
    int mt = w & 1;
    int ntbase = (w >> 1) * 8;
    int lrow = l & 15, q = l >> 4;

    v8s a[KT];
#pragma unroll
    for (int kt = 0; kt < KT; ++kt)
        a[kt] = *(const v8s*)&srcLDS[(mt * 16 + lrow) * srcStride + kt * 32 + q * 8];

    for (int p = 0; p < 4; ++p) {
        int nt0 = ntbase + 2 * p, nt1 = nt0 + 1;
        v4f acc0 = {0.f, 0.f, 0.f, 0.f}, acc1 = {0.f, 0.f, 0.f, 0.f};
#pragma unroll
        for (int kt = 0; kt < KT; ++kt) {
            v8s b0 = *(const v8s*)&wpack[(size_t)(nt0 * KT + kt) * 512 + l * 8];
            v8s b1 = *(const v8s*)&wpack[(size_t)(nt1 * KT + kt) * 512 + l * 8];
            acc0 = __builtin_amdgcn_mfma_f32_16x16x32_bf16(a[kt], b0, acc0, 0, 0, 0);
            acc1 = __builtin_amdgcn_mfma_f32_16x16x32_bf16(a[kt], b1, acc1, 0, 0, 0);
        }
#pragma unroll
        for (int r = 0; r < 4; ++r) {
            float x0 = acc0[r] * scale, x1 = acc1[r] * scale;
            if (SILU) {
                x0 = x0 / (1.f + __expf(-x0));
                x1 = x1 / (1.f + __expf(-x1));
            }
            int row = mt * 16 + q * 4 + r;
            dstLDS[row * H_STRIDE + nt0 * 16 + lrow] = f2bf(x0);
            dstLDS[row * H_STRIDE + nt1 * 16 + lrow] = f2bf(x1);
        }
    }
    __syncthreads();
}

// GEMM [32x256]@[256x128] from LDS A, then atomicAdd into out[r, col*4+cofs].
__device__ __forceinline__ void gemm_atomic(
    const ushort* __restrict__ wpack, const ushort* srcLDS,
    const int* s_rcv, float* __restrict__ out, int cofs)
{
    int t = threadIdx.x;
    int w = t >> 6, l = t & 63;
    int mt = w & 1;
    int ntbase = (w >> 1) * 4;
    int lrow = l & 15, q = l >> 4;
    v8s a[8];
#pragma unroll
    for (int kt = 0; kt < 8; ++kt)
        a[kt] = *(const v8s*)&srcLDS[(mt * 16 + lrow) * H_STRIDE + kt * 32 + q * 8];
#pragma unroll
    for (int pp = 0; pp < 2; ++pp) {
        int nt0 = ntbase + 2 * pp, nt1 = nt0 + 1;
        v4f acc0 = {0.f, 0.f, 0.f, 0.f}, acc1 = {0.f, 0.f, 0.f, 0.f};
#pragma unroll
        for (int kt = 0; kt < 8; ++kt) {
            v8s b0 = *(const v8s*)&wpack[(size_t)(nt0 * 8 + kt) * 512 + l * 8];
            v8s b1 = *(const v8s*)&wpack[(size_t)(nt1 * 8 + kt) * 512 + l * 8];
            acc0 = __builtin_amdgcn_mfma_f32_16x16x32_bf16(a[kt], b0, acc0, 0, 0, 0);
            acc1 = __builtin_amdgcn_mfma_f32_16x16x32_bf16(a[kt], b1, acc1, 0, 0, 0);
        }
        int col0 = nt0 * 16 + lrow, col1 = nt1 * 16 + lrow;
#pragma unroll
        for (int r = 0; r < 4; ++r) {
            int row = mt * 16 + q * 4 + r;
            int rcv = s_rcv[row];
            atomicAdd(&out[(size_t)rcv * 512 + col0 * 4 + cofs], fin(acc0[r] * OUT_SCALE));
            atomicAdd(&out[(size_t)rcv * 512 + col1 * 4 + cofs], fin(acc1[r] * OUT_SCALE));
        }
    }
}

// ---------------------------------------------------------------------------
// Edge-parallel fused kernel: 32 edges/block (E = 5000*32 exactly, no tail).
// MLP (4 MFMA layers) -> in-register quarter contraction -> mji in LDS ->
// 4 W_lin MFMA GEMMs -> fp32 atomicAdd into out_msg. No CSR, no spill-heavy
// per-node loop, uniform work.
// ---------------------------------------------------------------------------
__global__ __launch_bounds__(256, 2) void edge_msg_kernel(
    const int* __restrict__ eidx,
    const float* __restrict__ ef, const float* __restrict__ ea,
    const ushort* __restrict__ down,
    const ushort* __restrict__ u0, const ushort* __restrict__ u1,
    const ushort* __restrict__ w1p, const ushort* __restrict__ w2p,
    const ushort* __restrict__ w3p, const ushort* __restrict__ w4p,
    const ushort* __restrict__ wl0p, const ushort* __restrict__ wl1p,
    float* __restrict__ out_msg)
{
    __shared__ __align__(16) ushort s_aug[32 * 168];     // 10,752 B
    __shared__ __align__(16) ushort s_hA[32 * H_STRIDE]; // 16,896 B
    __shared__ __align__(16) ushort s_hB[32 * H_STRIDE]; // 16,896 B
    __shared__ __align__(16) ushort s_q1[32 * 136];      //  8,704 B (w1*xs0)
    __shared__ __align__(16) ushort s_q2[32 * 136];      //  8,704 B (w2)
    __shared__ int s_snd[32];
    __shared__ int s_rcv[32];
    __shared__ float s_y[32][4];

    int t = threadIdx.x;
    int e0 = blockIdx.x * 32;

    if (t < 32) {
        int e = e0 + t;
        int s = eidx[e];
        int r = eidx[N_EDGES + e];
        if (s < 0) s = 0; if (s >= N_NODES) s = N_NODES - 1;
        if (r < 0) r = 0; if (r >= N_NODES) r = N_NODES - 1;
        s_snd[t] = s; s_rcv[t] = r;
        s_y[t][0] = fin(ea[(size_t)e * 4 + 0]);
        s_y[t][1] = fin(ea[(size_t)e * 4 + 1]);
        s_y[t][2] = fin(ea[(size_t)e * 4 + 2]);
        s_y[t][3] = fin(ea[(size_t)e * 4 + 3]);
    }
    __syncthreads();
    // aug = [edge_feats(8) | down[sender](64) | down[receiver](64) | 0-pad]
    for (int i = t; i < 32 * 168; i += 256) {
        int e = i / 168, cc = i - e * 168;
        ushort vv = 0;
        if (cc < 8)        vv = f2bf(ef[(size_t)(e0 + e) * 8 + cc]);
        else if (cc < 72)  vv = down[(size_t)s_snd[e] * 64 + (cc - 8)];
        else if (cc < 136) vv = down[(size_t)s_rcv[e] * 64 + (cc - 72)];
        s_aug[i] = vv;
    }
    __syncthreads();
    gemm_layer<5, true>(w1p, s_aug, 168, s_hA, S_MLP1);
    gemm_layer<8, true>(w2p, s_hA, H_STRIDE, s_hB, S_MLP);
    gemm_layer<8, true>(w3p, s_hB, H_STRIDE, s_hA, S_MLP);   // h -> s_hA

    // ---- layer 4 quarters, contracted in-register ----
    int w = t >> 6, l = t & 63;
    int mt = w & 1;
    int lrow = l & 15, q = l >> 4;
    v8s a4[8];
#pragma unroll
    for (int kt = 0; kt < 8; ++kt)
        a4[kt] = *(const v8s*)&s_hA[(mt * 16 + lrow) * H_STRIDE + kt * 32 + q * 8];

    for (int qd = 0; qd < 4; ++qd) {
#pragma unroll
        for (int pp = 0; pp < 2; ++pp) {
            int nt0 = qd * 8 + (w >> 1) * 4 + pp * 2;
            int nt1 = nt0 + 1;
            v4f acc0 = {0.f, 0.f, 0.f, 0.f}, acc1 = {0.f, 0.f, 0.f, 0.f};
#pragma unroll
            for (int kt = 0; kt < 8; ++kt) {
                v8s b0 = *(const v8s*)&w4p[(size_t)(nt0 * 8 + kt) * 512 + l * 8];
                v8s b1 = *(const v8s*)&w4p[(size_t)(nt1 * 8 + kt) * 512 + l * 8];
                acc0 = __builtin_amdgcn_mfma_f32_16x16x32_bf16(a4[kt], b0, acc0, 0, 0, 0);
                acc1 = __builtin_amdgcn_mfma_f32_16x16x32_bf16(a4[kt], b1, acc1, 0, 0, 0);
            }
            int col0 = (nt0 * 16 + lrow) & 127;
            int col1 = col0 + 16;
#pragma unroll
            for (int r = 0; r < 4; ++r) {
                int row = mt * 16 + q * 4 + r;
                int snd = s_snd[row];
                float v0 = acc0[r] * S_MLP, v1 = acc1[r] * S_MLP;
                if (qd == 0) {            // mji0 cols 0-127: w0*xs0*y0
                    float y0 = s_y[row][0];
                    s_hB[row * H_STRIDE + col0] =
                        f2bf(v0 * bf2f(u0[(size_t)snd * 128 + col0]) * y0);
                    s_hB[row * H_STRIDE + col1] =
                        f2bf(v1 * bf2f(u0[(size_t)snd * 128 + col1]) * y0);
                } else if (qd == 1) {     // q1 = w1*xs0
                    s_q1[row * 136 + col0] = f2bf(v0 * bf2f(u0[(size_t)snd * 128 + col0]));
                    s_q1[row * 136 + col1] = f2bf(v1 * bf2f(u0[(size_t)snd * 128 + col1]));
                } else if (qd == 2) {     // q2 = w2
                    s_q2[row * 136 + col0] = f2bf(v0);
                    s_q2[row * 136 + col1] = f2bf(v1);
                } else {                  // mji0 cols 128-255: w3*(xs1.y1)/sqrt3
                    size_t ub0 = (size_t)snd * 384 + col0 * 3;
                    size_t ub1 = (size_t)snd * 384 + col1 * 3;
                    float d0 = bf2f(u1[ub0]) * s_y[row][1] + bf2f(u1[ub0 + 1]) * s_y[row][2]
                             + bf2f(u1[ub0 + 2]) * s_y[row][3];
                    float d1 = bf2f(u1[ub1]) * s_y[row][1] + bf2f(u1[ub1 + 1]) * s_y[row][2]
                             + bf2f(u1[ub1 + 2]) * s_y[row][3];
                    s_hB[row * H_STRIDE + 128 + col0] = f2bf(v0 * d0 * INV_SQRT3);
                    s_hB[row * H_STRIDE + 128 + col1] = f2bf(v1 * d1 * INV_SQRT3);
                }
            }
        }
    }
    __syncthreads();

    // msg0 = mji0 @ WL0 -> out col*4+0
    gemm_atomic(wl0p, s_hB, s_rcv, out_msg, 0);
    __syncthreads();

    // msg1_i = mji1_i @ WL1 -> out col*4+1+i  (mji1_i built in s_hA)
    for (int i = 0; i < 3; ++i) {
        for (int idx = t; idx < 32 * 256; idx += 256) {
            int e = idx >> 8, c = idx & 255;
            float val;
            if (c < 128) {
                val = bf2f(s_q1[e * 136 + c]) * s_y[e][1 + i];
            } else {
                int cc = c - 128;
                val = bf2f(s_q2[e * 136 + cc])
                    * bf2f(u1[(size_t)s_snd[e] * 384 + cc * 3 + i]) * s_y[e][0];
            }
            s_hA[e * H_STRIDE + c] = f2bf(val);
        }
        __syncthreads();
        gemm_atomic(wl1p, s_hA, s_rcv, out_msg, 1 + i);
        __syncthreads();
    }
}

// ---------------------------------------------------------------------------
extern "C" void kernel_launch(void* const* d_in, const int* in_sizes, int n_in,
                              void* d_out, int out_size, void* d_ws, size_t ws_size,
                              hipStream_t stream)
{
    (void)d_ws; (void)ws_size;

    const float* node_feats = (const float*)d_in[1];
    const float* edge_attrs = (const float*)d_in[2];
    const float* edge_feats = (const float*)d_in[3];
    const int*   edge_index = (const int*)d_in[4];
    const float* W_up0  = (const float*)d_in[5];
    const float* W_up1  = (const float*)d_in[6];
    const float* W_down = (const float*)d_in[7];
    const float* mlp_w1 = (const float*)d_in[8];
    const float* mlp_w2 = (const float*)d_in[9];
    const float* mlp_w3 = (const float*)d_in[10];
    const float* mlp_w4 = (const float*)d_in[11];
    const float* W_lin0 = (const float*)d_in[12];
    const float* W_lin1 = (const float*)d_in[13];
    const float* W_skip0 = (const float*)d_in[14];
    const float* W_skip1 = (const float*)d_in[15];

    // d_out fp32: [message: 20,480,000 B][sc: 20,480,000 B]
    char* S = (char*)d_out + 20480000;   // sc half = scratch until node_sc

    // Scratch inside S (total 12,257,280 B < 20,480,000 B):
    ushort* u0    = (ushort*)(S + 0);           //  2,560,000 B
    ushort* down  = (ushort*)(S + 2560000);     //  1,280,000 B
    ushort* u1    = (ushort*)(S + 3840000);     //  7,680,000 B
    ushort* w1p   = (ushort*)(S + 11520000);    //     81,920 B
    ushort* w2p   = (ushort*)(S + 11601920);    //    131,072 B
    ushort* w3p   = (ushort*)(S + 11732992);    //    131,072 B
    ushort* w4p   = (ushort*)(S + 11864064);    //    262,144 B
    ushort* wl0p  = (ushort*)(S + 12126208);    //     65,536 B
    ushort* wl1p  = (ushort*)(S + 12191744);    //     65,536 B

    float* out_msg = (float*)d_out;
    float* out_sc  = (float*)d_out + (size_t)N_NODES * 512;

    // zero the message half (atomic accumulation target)
    hipMemsetAsync(out_msg, 0, 20480000, stream);

    pack_kernel<<<1440, 256, 0, stream>>>(mlp_w1, mlp_w2, mlp_w3, mlp_w4, W_lin0, W_lin1,
                                          w1p, w2p, w3p, w4p, wl0p, wl1p);
    node_uud_kernel<<<N_NODES, 256, 0, stream>>>(node_feats, W_up0, W_up1, W_down, u0, u1, down);
    edge_msg_kernel<<<N_EDGES / 32, 256, 0, stream>>>(edge_index, edge_feats, edge_attrs,
                                                      down, u0, u1,
                                                      w1p, w2p, w3p, w4p, wl0p, wl1p, out_msg);
    node_sc_kernel<<<N_NODES, 256, 0, stream>>>(node_feats, W_skip0, W_skip1, out_sc);
}

// Round 8
// 1143.111 us; speedup vs baseline: 2.7780x; 1.2677x over previous
//
#include <hip/hip_runtime.h>
#include <hip/hip_bf16.h>

#define N_NODES 10000
#define N_EDGES 160000

typedef short v8s __attribute__((ext_vector_type(8)));
typedef float v4f __attribute__((ext_vector_type(4)));

__device__ __forceinline__ float bf2f(ushort u) {
    union { unsigned i; float f; } x; x.i = ((unsigned)u) << 16; return x.f;
}
__device__ __forceinline__ float fin(float x) {
    return (x == x) ? fminf(fmaxf(x, -1e30f), 1e30f) : 0.f;
}
__device__ __forceinline__ ushort f2bf(float f) {
    union { unsigned i; float f; } x; x.f = fin(f);
    unsigned i = x.i;
    unsigned r = (i + 0x7fffu + ((i >> 16) & 1u)) >> 16;
    return (ushort)r;
}

#define INV_C 0.08838834764831845f      /* 1/sqrt(128) */
#define S_MLP1 0.08574929257125442f     /* 1/sqrt(136) */
#define S_MLP 0.0625f                   /* 1/16 */
#define INV_SQRT3 0.5773502691896258f
#define OUT_SCALE 0.00390625f           /* (1/sqrt(256))/16 */

// ---------------------------------------------------------------------------
// Weight pre-pack: fp32 -> bf16 MFMA B-fragment order.
// B-frag (16x16x32): lane l holds B[k = kt*32 + (l>>4)*8 + j][n = nt*16 + (l&15)]
// packed flat index: ((nt*KT + kt)*64 + l)*8 + j
// ---------------------------------------------------------------------------
__global__ __launch_bounds__(256) void pack_kernel(
    const float* __restrict__ w1, const float* __restrict__ w2,
    const float* __restrict__ w3, const float* __restrict__ w4,
    const float* __restrict__ wl0, const float* __restrict__ wl1,
    ushort* __restrict__ w1p, ushort* __restrict__ w2p,
    ushort* __restrict__ w3p, ushort* __restrict__ w4p,
    ushort* __restrict__ wl0p, ushort* __restrict__ wl1p)
{
    int idx = blockIdx.x * 256 + threadIdx.x;
    const float* W; ushort* D; int KT, Kreal, Nn, id;
    if (idx < 40960)       { W = w1;  D = w1p;  KT = 5; Kreal = 136; Nn = 256; id = idx; }
    else if (idx < 106496) { W = w2;  D = w2p;  KT = 8; Kreal = 256; Nn = 256; id = idx - 40960; }
    else if (idx < 172032) { W = w3;  D = w3p;  KT = 8; Kreal = 256; Nn = 256; id = idx - 106496; }
    else if (idx < 303104) { W = w4;  D = w4p;  KT = 8; Kreal = 256; Nn = 512; id = idx - 172032; }
    else if (idx < 335872) { W = wl0; D = wl0p; KT = 8; Kreal = 256; Nn = 128; id = idx - 303104; }
    else                   { W = wl1; D = wl1p; KT = 8; Kreal = 256; Nn = 128; id = idx - 335872; }
    int j = id & 7, lane = (id >> 3) & 63, tt = id >> 9;
    int kt = tt % KT, nt = tt / KT;
    int k = kt * 32 + ((lane >> 4) << 3) + j;
    int nn = nt * 16 + (lane & 15);
    D[id] = (k < Kreal) ? f2bf(W[k * Nn + nn]) : (ushort)0;
}

// ---------------------------------------------------------------------------
// Node up/down projections (fp32 in): u0, u1, down -> bf16 scratch.
// ---------------------------------------------------------------------------
__global__ __launch_bounds__(256) void node_uud_kernel(
    const float* __restrict__ nf,
    const float* __restrict__ Wu0, const float* __restrict__ Wu1,
    const float* __restrict__ Wd,
    ushort* __restrict__ u0, ushort* __restrict__ u1,
    ushort* __restrict__ down)
{
    __shared__ float x[512];
    int n = blockIdx.x, t = threadIdx.x;
    for (int i = t; i < 512; i += 256) x[i] = nf[(size_t)n * 512 + i];
    __syncthreads();
    int v = t & 127;
    if (t < 128) {
        float acc = 0.f;
        for (int u = 0; u < 128; ++u) acc += x[u] * Wu0[u * 128 + v];
        u0[(size_t)n * 128 + v] = f2bf(acc * INV_C);
        if (t < 64) {
            float a3 = 0.f;
            for (int u = 0; u < 128; ++u) a3 += x[u] * Wd[u * 64 + t];
            down[(size_t)n * 64 + t] = f2bf(a3 * INV_C);
        }
    } else {
        for (int i = 0; i < 3; ++i) {
            float a2 = 0.f;
            for (int u = 0; u < 128; ++u) a2 += x[128 + u * 3 + i] * Wu1[u * 128 + v];
            u1[(size_t)n * 384 + v * 3 + i] = f2bf(a2 * INV_C);
        }
    }
}

// ---------------------------------------------------------------------------
// Skip connection (runs LAST — overwrites scratch with fp32 sc output).
// ---------------------------------------------------------------------------
__global__ __launch_bounds__(256) void node_sc_kernel(
    const float* __restrict__ nf,
    const float* __restrict__ Ws0, const float* __restrict__ Ws1,
    float* __restrict__ out_sc)
{
    __shared__ float x[512];
    int n = blockIdx.x, t = threadIdx.x;
    for (int i = t; i < 512; i += 256) x[i] = nf[(size_t)n * 512 + i];
    __syncthreads();
    int v = t & 127;
    if (t < 128) {
        float acc = 0.f;
        for (int u = 0; u < 128; ++u) acc += x[u] * Ws0[u * 128 + v];
        out_sc[(size_t)n * 512 + v] = fin(acc * INV_C);
    } else {
        for (int i = 0; i < 3; ++i) {
            float a2 = 0.f;
            for (int u = 0; u < 128; ++u) a2 += x[128 + u * 3 + i] * Ws1[u * 128 + v];
            out_sc[(size_t)n * 512 + 128 + v * 3 + i] = fin(a2 * INV_C);
        }
    }
}

// ---------------------------------------------------------------------------
// CSR build (receiver-sorted edge list) — path A only.
// ---------------------------------------------------------------------------
__global__ __launch_bounds__(256) void hist_kernel(const int* __restrict__ eidx, int* __restrict__ counts)
{
    int e = blockIdx.x * 256 + threadIdx.x;
    int r = eidx[N_EDGES + e];
    if (r < 0) r = 0; if (r >= N_NODES) r = N_NODES - 1;
    atomicAdd(&counts[r], 1);
}

__global__ __launch_bounds__(1024) void scan_kernel(const int* __restrict__ counts, int* __restrict__ offs)
{
    __shared__ int buf[1024];
    __shared__ int base_s;
    int t = threadIdx.x;
    if (t == 0) { base_s = 0; offs[0] = 0; }
    __syncthreads();
    for (int chunk = 0; chunk < (N_NODES + 1023) / 1024; ++chunk) {
        int i = chunk * 1024 + t;
        int vv = (i < N_NODES) ? counts[i] : 0;
        buf[t] = vv;
        __syncthreads();
        for (int off = 1; off < 1024; off <<= 1) {
            int xv = (t >= off) ? buf[t - off] : 0;
            __syncthreads();
            buf[t] += xv;
            __syncthreads();
        }
        int incl = buf[t];
        int base = base_s;
        __syncthreads();
        if (i < N_NODES) offs[i + 1] = base + incl;
        if (t == 1023) base_s = base + incl;
        __syncthreads();
    }
}

__global__ __launch_bounds__(256) void fill_kernel(
    const int* __restrict__ eidx, const int* __restrict__ offs,
    int* __restrict__ cnt2, int* __restrict__ esort)
{
    int e = blockIdx.x * 256 + threadIdx.x;
    int r = eidx[N_EDGES + e];
    if (r < 0) r = 0; if (r >= N_NODES) r = N_NODES - 1;
    int k = atomicAdd(&cnt2[r], 1);
    int pos = offs[r] + k;
    if (pos < 0) pos = 0; if (pos >= N_EDGES) pos = N_EDGES - 1;
    esort[pos] = e;
}

// ---------------------------------------------------------------------------
// Hidden-layer MFMA GEMM: 32 edges x 256 out, bf16 LDS->LDS.
// A-frag: lane l holds A[m=l&15][k=(l>>4)*8+j]; C/D: row=(l>>4)*4+r, col=l&15.
// ---------------------------------------------------------------------------
#define H_STRIDE 264

template <int KT, bool SILU>
__device__ __forceinline__ void gemm_layer(
    const ushort* __restrict__ wpack, const ushort* srcLDS, int srcStride,
    ushort* dstLDS, float scale)
{
    int t = threadIdx.x;
    int w = t >> 6, l = t & 63;
    int mt = w & 1;
    int ntbase = (w >> 1) * 8;
    int lrow = l & 15, q = l >> 4;

    v8s a[KT];
#pragma unroll
    for (int kt = 0; kt < KT; ++kt)
        a[kt] = *(const v8s*)&srcLDS[(mt * 16 + lrow) * srcStride + kt * 32 + q * 8];

    for (int p = 0; p < 4; ++p) {
        int nt0 = ntbase + 2 * p, nt1 = nt0 + 1;
        v4f acc0 = {0.f, 0.f, 0.f, 0.f}, acc1 = {0.f, 0.f, 0.f, 0.f};
#pragma unroll
        for (int kt = 0; kt < KT; ++kt) {
            v8s b0 = *(const v8s*)&wpack[(size_t)(nt0 * KT + kt) * 512 + l * 8];
            v8s b1 = *(const v8s*)&wpack[(size_t)(nt1 * KT + kt) * 512 + l * 8];
            acc0 = __builtin_amdgcn_mfma_f32_16x16x32_bf16(a[kt], b0, acc0, 0, 0, 0);
            acc1 = __builtin_amdgcn_mfma_f32_16x16x32_bf16(a[kt], b1, acc1, 0, 0, 0);
        }
#pragma unroll
        for (int r = 0; r < 4; ++r) {
            float x0 = acc0[r] * scale, x1 = acc1[r] * scale;
            if (SILU) {
                x0 = x0 / (1.f + __expf(-x0));
                x1 = x1 / (1.f + __expf(-x1));
            }
            int row = mt * 16 + q * 4 + r;
            dstLDS[row * H_STRIDE + nt0 * 16 + lrow] = f2bf(x0);
            dstLDS[row * H_STRIDE + nt1 * 16 + lrow] = f2bf(x1);
        }
    }
    __syncthreads();
}

// GEMM [32x256]@[256x128]; output either atomicAdd into out_msg (path B) or
// bf16 store into tpw[e][512] (path A).
template <bool ATOMIC>
__device__ __forceinline__ void gemm_out(
    const ushort* __restrict__ wpack, const ushort* srcLDS,
    const int* s_rcv, float* __restrict__ out, ushort* __restrict__ tpw,
    int e0, int cofs)
{
    int t = threadIdx.x;
    int w = t >> 6, l = t & 63;
    int mt = w & 1;
    int ntbase = (w >> 1) * 4;
    int lrow = l & 15, q = l >> 4;
    v8s a[8];
#pragma unroll
    for (int kt = 0; kt < 8; ++kt)
        a[kt] = *(const v8s*)&srcLDS[(mt * 16 + lrow) * H_STRIDE + kt * 32 + q * 8];
#pragma unroll
    for (int pp = 0; pp < 2; ++pp) {
        int nt0 = ntbase + 2 * pp, nt1 = nt0 + 1;
        v4f acc0 = {0.f, 0.f, 0.f, 0.f}, acc1 = {0.f, 0.f, 0.f, 0.f};
#pragma unroll
        for (int kt = 0; kt < 8; ++kt) {
            v8s b0 = *(const v8s*)&wpack[(size_t)(nt0 * 8 + kt) * 512 + l * 8];
            v8s b1 = *(const v8s*)&wpack[(size_t)(nt1 * 8 + kt) * 512 + l * 8];
            acc0 = __builtin_amdgcn_mfma_f32_16x16x32_bf16(a[kt], b0, acc0, 0, 0, 0);
            acc1 = __builtin_amdgcn_mfma_f32_16x16x32_bf16(a[kt], b1, acc1, 0, 0, 0);
        }
        int col0 = nt0 * 16 + lrow, col1 = nt1 * 16 + lrow;
#pragma unroll
        for (int r = 0; r < 4; ++r) {
            int row = mt * 16 + q * 4 + r;
            if constexpr (ATOMIC) {
                int rcv = s_rcv[row];
                atomicAdd(&out[(size_t)rcv * 512 + col0 * 4 + cofs], fin(acc0[r] * OUT_SCALE));
                atomicAdd(&out[(size_t)rcv * 512 + col1 * 4 + cofs], fin(acc1[r] * OUT_SCALE));
            } else {
                size_t base = (size_t)(e0 + row) * 512;
                tpw[base + col0 * 4 + cofs] = f2bf(acc0[r] * OUT_SCALE);
                tpw[base + col1 * 4 + cofs] = f2bf(acc1[r] * OUT_SCALE);
            }
        }
    }
}

// ---------------------------------------------------------------------------
// Edge-parallel fused kernel: 32 edges/block. MLP (4 MFMA layers) -> quarter
// contraction -> mji in LDS -> 4 W_lin MFMA GEMMs -> output per template.
// ---------------------------------------------------------------------------
template <bool ATOMIC>
__global__ __launch_bounds__(256, 2) void edge_msg_kernel(
    const int* __restrict__ eidx,
    const float* __restrict__ ef, const float* __restrict__ ea,
    const ushort* __restrict__ down,
    const ushort* __restrict__ u0, const ushort* __restrict__ u1,
    const ushort* __restrict__ w1p, const ushort* __restrict__ w2p,
    const ushort* __restrict__ w3p, const ushort* __restrict__ w4p,
    const ushort* __restrict__ wl0p, const ushort* __restrict__ wl1p,
    float* __restrict__ out_msg, ushort* __restrict__ tpw)
{
    __shared__ __align__(16) ushort s_aug[32 * 168];
    __shared__ __align__(16) ushort s_hA[32 * H_STRIDE];
    __shared__ __align__(16) ushort s_hB[32 * H_STRIDE];
    __shared__ __align__(16) ushort s_q1[32 * 136];
    __shared__ __align__(16) ushort s_q2[32 * 136];
    __shared__ int s_snd[32];
    __shared__ int s_rcv[32];
    __shared__ float s_y[32][4];

    int t = threadIdx.x;
    int e0 = blockIdx.x * 32;

    if (t < 32) {
        int e = e0 + t;
        int s = eidx[e];
        int r = eidx[N_EDGES + e];
        if (s < 0) s = 0; if (s >= N_NODES) s = N_NODES - 1;
        if (r < 0) r = 0; if (r >= N_NODES) r = N_NODES - 1;
        s_snd[t] = s; s_rcv[t] = r;
        s_y[t][0] = fin(ea[(size_t)e * 4 + 0]);
        s_y[t][1] = fin(ea[(size_t)e * 4 + 1]);
        s_y[t][2] = fin(ea[(size_t)e * 4 + 2]);
        s_y[t][3] = fin(ea[(size_t)e * 4 + 3]);
    }
    __syncthreads();
    for (int i = t; i < 32 * 168; i += 256) {
        int e = i / 168, cc = i - e * 168;
        ushort vv = 0;
        if (cc < 8)        vv = f2bf(ef[(size_t)(e0 + e) * 8 + cc]);
        else if (cc < 72)  vv = down[(size_t)s_snd[e] * 64 + (cc - 8)];
        else if (cc < 136) vv = down[(size_t)s_rcv[e] * 64 + (cc - 72)];
        s_aug[i] = vv;
    }
    __syncthreads();
    gemm_layer<5, true>(w1p, s_aug, 168, s_hA, S_MLP1);
    gemm_layer<8, true>(w2p, s_hA, H_STRIDE, s_hB, S_MLP);
    gemm_layer<8, true>(w3p, s_hB, H_STRIDE, s_hA, S_MLP);

    // ---- layer 4 quarters, contracted in-register ----
    int w = t >> 6, l = t & 63;
    int mt = w & 1;
    int lrow = l & 15, q = l >> 4;
    v8s a4[8];
#pragma unroll
    for (int kt = 0; kt < 8; ++kt)
        a4[kt] = *(const v8s*)&s_hA[(mt * 16 + lrow) * H_STRIDE + kt * 32 + q * 8];

    for (int qd = 0; qd < 4; ++qd) {
#pragma unroll
        for (int pp = 0; pp < 2; ++pp) {
            int nt0 = qd * 8 + (w >> 1) * 4 + pp * 2;
            int nt1 = nt0 + 1;
            v4f acc0 = {0.f, 0.f, 0.f, 0.f}, acc1 = {0.f, 0.f, 0.f, 0.f};
#pragma unroll
            for (int kt = 0; kt < 8; ++kt) {
                v8s b0 = *(const v8s*)&w4p[(size_t)(nt0 * 8 + kt) * 512 + l * 8];
                v8s b1 = *(const v8s*)&w4p[(size_t)(nt1 * 8 + kt) * 512 + l * 8];
                acc0 = __builtin_amdgcn_mfma_f32_16x16x32_bf16(a4[kt], b0, acc0, 0, 0, 0);
                acc1 = __builtin_amdgcn_mfma_f32_16x16x32_bf16(a4[kt], b1, acc1, 0, 0, 0);
            }
            int col0 = (nt0 * 16 + lrow) & 127;
            int col1 = col0 + 16;
#pragma unroll
            for (int r = 0; r < 4; ++r) {
                int row = mt * 16 + q * 4 + r;
                int snd = s_snd[row];
                float v0 = acc0[r] * S_MLP, v1 = acc1[r] * S_MLP;
                if (qd == 0) {
                    float y0 = s_y[row][0];
                    s_hB[row * H_STRIDE + col0] =
                        f2bf(v0 * bf2f(u0[(size_t)snd * 128 + col0]) * y0);
                    s_hB[row * H_STRIDE + col1] =
                        f2bf(v1 * bf2f(u0[(size_t)snd * 128 + col1]) * y0);
                } else if (qd == 1) {
                    s_q1[row * 136 + col0] = f2bf(v0 * bf2f(u0[(size_t)snd * 128 + col0]));
                    s_q1[row * 136 + col1] = f2bf(v1 * bf2f(u0[(size_t)snd * 128 + col1]));
                } else if (qd == 2) {
                    s_q2[row * 136 + col0] = f2bf(v0);
                    s_q2[row * 136 + col1] = f2bf(v1);
                } else {
                    size_t ub0 = (size_t)snd * 384 + col0 * 3;
                    size_t ub1 = (size_t)snd * 384 + col1 * 3;
                    float d0 = bf2f(u1[ub0]) * s_y[row][1] + bf2f(u1[ub0 + 1]) * s_y[row][2]
                             + bf2f(u1[ub0 + 2]) * s_y[row][3];
                    float d1 = bf2f(u1[ub1]) * s_y[row][1] + bf2f(u1[ub1 + 1]) * s_y[row][2]
                             + bf2f(u1[ub1 + 2]) * s_y[row][3];
                    s_hB[row * H_STRIDE + 128 + col0] = f2bf(v0 * d0 * INV_SQRT3);
                    s_hB[row * H_STRIDE + 128 + col1] = f2bf(v1 * d1 * INV_SQRT3);
                }
            }
        }
    }
    __syncthreads();

    gemm_out<ATOMIC>(wl0p, s_hB, s_rcv, out_msg, tpw, e0, 0);
    __syncthreads();

    for (int i = 0; i < 3; ++i) {
        for (int idx = t; idx < 32 * 256; idx += 256) {
            int e = idx >> 8, c = idx & 255;
            float val;
            if (c < 128) {
                val = bf2f(s_q1[e * 136 + c]) * s_y[e][1 + i];
            } else {
                int cc = c - 128;
                val = bf2f(s_q2[e * 136 + cc])
                    * bf2f(u1[(size_t)s_snd[e] * 384 + cc * 3 + i]) * s_y[e][0];
            }
            s_hA[e * H_STRIDE + c] = f2bf(val);
        }
        __syncthreads();
        gemm_out<ATOMIC>(wl1p, s_hA, s_rcv, out_msg, tpw, e0, 1 + i);
        __syncthreads();
    }
}

// ---------------------------------------------------------------------------
// Path A: CSR gather — out_msg[n] = sum of tpw rows of n's edges. No atomics.
// ---------------------------------------------------------------------------
__global__ __launch_bounds__(256) void gather_kernel(
    const int* __restrict__ offs, const int* __restrict__ esort,
    const ushort* __restrict__ tpw, float* __restrict__ out_msg)
{
    int n = blockIdx.x, t = threadIdx.x;
    int beg = offs[n];
    if (beg < 0) beg = 0; if (beg > N_EDGES) beg = N_EDGES;
    int end = offs[n + 1];
    if (end < beg) end = beg; if (end > N_EDGES) end = N_EDGES;
    float a0 = 0.f, a1 = 0.f;
    for (int j = beg; j < end; ++j) {
        int e = esort[j];
        if (e < 0) e = 0; if (e >= N_EDGES) e = N_EDGES - 1;
        const ushort* row = tpw + (size_t)e * 512;
        ushort2 v = *(const ushort2*)&row[t * 2];
        a0 += bf2f(v.x); a1 += bf2f(v.y);
    }
    out_msg[(size_t)n * 512 + t * 2 + 0] = a0;
    out_msg[(size_t)n * 512 + t * 2 + 1] = a1;
}

// ---------------------------------------------------------------------------
extern "C" void kernel_launch(void* const* d_in, const int* in_sizes, int n_in,
                              void* d_out, int out_size, void* d_ws, size_t ws_size,
                              hipStream_t stream)
{
    const float* node_feats = (const float*)d_in[1];
    const float* edge_attrs = (const float*)d_in[2];
    const float* edge_feats = (const float*)d_in[3];
    const int*   edge_index = (const int*)d_in[4];
    const float* W_up0  = (const float*)d_in[5];
    const float* W_up1  = (const float*)d_in[6];
    const float* W_down = (const float*)d_in[7];
    const float* mlp_w1 = (const float*)d_in[8];
    const float* mlp_w2 = (const float*)d_in[9];
    const float* mlp_w3 = (const float*)d_in[10];
    const float* mlp_w4 = (const float*)d_in[11];
    const float* W_lin0 = (const float*)d_in[12];
    const float* W_lin1 = (const float*)d_in[13];
    const float* W_skip0 = (const float*)d_in[14];
    const float* W_skip1 = (const float*)d_in[15];

    // d_out fp32: [message: 20,480,000 B][sc: 20,480,000 B]
    char* S = (char*)d_out + 20480000;   // sc half = scratch until node_sc

    ushort* u0    = (ushort*)(S + 0);           //  2,560,000 B
    ushort* down  = (ushort*)(S + 2560000);     //  1,280,000 B
    ushort* u1    = (ushort*)(S + 3840000);     //  7,680,000 B
    ushort* w1p   = (ushort*)(S + 11520000);    //     81,920 B
    ushort* w2p   = (ushort*)(S + 11601920);    //    131,072 B
    ushort* w3p   = (ushort*)(S + 11732992);    //    131,072 B
    ushort* w4p   = (ushort*)(S + 11864064);    //    262,144 B
    ushort* wl0p  = (ushort*)(S + 12126208);    //     65,536 B
    ushort* wl1p  = (ushort*)(S + 12191744);    //     65,536 B
    int*    offs  = (int*)(S + 12257280);       //     40,032 B
    int*    esort = (int*)(S + 12297312);       //    640,000 B
    int*    counts= (int*)(S + 12937312);       //     40,000 B
    int*    cnt2  = (int*)(S + 12977312);       //     40,000 B -> 13,017,312

    float* out_msg = (float*)d_out;
    float* out_sc  = (float*)d_out + (size_t)N_NODES * 512;

    const size_t TPW_BYTES = (size_t)N_EDGES * 512 * 2;   // 163,840,000
    bool bigws = (ws_size >= TPW_BYTES) && (d_ws != nullptr);
    ushort* tpw = (ushort*)d_ws;

    pack_kernel<<<1440, 256, 0, stream>>>(mlp_w1, mlp_w2, mlp_w3, mlp_w4, W_lin0, W_lin1,
                                          w1p, w2p, w3p, w4p, wl0p, wl1p);
    node_uud_kernel<<<N_NODES, 256, 0, stream>>>(node_feats, W_up0, W_up1, W_down, u0, u1, down);

    if (bigws) {
        // Path A: per-edge messages to tpw (coalesced stores), CSR gather (0 atomics).
        hipMemsetAsync(counts, 0, 80000, stream);
        hist_kernel<<<N_EDGES / 256, 256, 0, stream>>>(edge_index, counts);
        scan_kernel<<<1, 1024, 0, stream>>>(counts, offs);
        fill_kernel<<<N_EDGES / 256, 256, 0, stream>>>(edge_index, offs, cnt2, esort);
        edge_msg_kernel<false><<<N_EDGES / 32, 256, 0, stream>>>(edge_index, edge_feats, edge_attrs,
            down, u0, u1, w1p, w2p, w3p, w4p, wl0p, wl1p, out_msg, tpw);
        gather_kernel<<<N_NODES, 256, 0, stream>>>(offs, esort, tpw, out_msg);
    } else {
        // Path B: round-7 atomic scatter (no regression fallback).
        hipMemsetAsync(out_msg, 0, 20480000, stream);
        edge_msg_kernel<true><<<N_EDGES / 32, 256, 0, stream>>>(edge_index, edge_feats, edge_attrs,
            down, u0, u1, w1p, w2p, w3p, w4p, wl0p, wl1p, out_msg, tpw);
    }
    node_sc_kernel<<<N_NODES, 256, 0, stream>>>(node_feats, W_skip0, W_skip1, out_sc);
}

// Round 9
// 1092.497 us; speedup vs baseline: 2.9067x; 1.0463x over previous
//
#include <hip/hip_runtime.h>
#include <hip/hip_bf16.h>

#define N_NODES 10000
#define N_EDGES 160000
#define TPW_PLANE ((size_t)N_EDGES * 128)

typedef short v8s __attribute__((ext_vector_type(8)));
typedef float v4f __attribute__((ext_vector_type(4)));

__device__ __forceinline__ float bf2f(ushort u) {
    union { unsigned i; float f; } x; x.i = ((unsigned)u) << 16; return x.f;
}
__device__ __forceinline__ float fin(float x) {
    return (x == x) ? fminf(fmaxf(x, -1e30f), 1e30f) : 0.f;
}
__device__ __forceinline__ ushort f2bf(float f) {
    union { unsigned i; float f; } x; x.f = fin(f);
    unsigned i = x.i;
    unsigned r = (i + 0x7fffu + ((i >> 16) & 1u)) >> 16;
    return (ushort)r;
}

#define INV_C 0.08838834764831845f      /* 1/sqrt(128) */
#define S_MLP1 0.08574929257125442f     /* 1/sqrt(136) */
#define S_MLP 0.0625f                   /* 1/16 */
#define INV_SQRT3 0.5773502691896258f
#define OUT_SCALE 0.00390625f           /* (1/sqrt(256))/16 */

// ---------------------------------------------------------------------------
// Weight pre-pack: fp32 -> bf16 MFMA B-fragment order.
// ---------------------------------------------------------------------------
__global__ __launch_bounds__(256) void pack_kernel(
    const float* __restrict__ w1, const float* __restrict__ w2,
    const float* __restrict__ w3, const float* __restrict__ w4,
    const float* __restrict__ wl0, const float* __restrict__ wl1,
    ushort* __restrict__ w1p, ushort* __restrict__ w2p,
    ushort* __restrict__ w3p, ushort* __restrict__ w4p,
    ushort* __restrict__ wl0p, ushort* __restrict__ wl1p)
{
    int idx = blockIdx.x * 256 + threadIdx.x;
    const float* W; ushort* D; int KT, Kreal, Nn, id;
    if (idx < 40960)       { W = w1;  D = w1p;  KT = 5; Kreal = 136; Nn = 256; id = idx; }
    else if (idx < 106496) { W = w2;  D = w2p;  KT = 8; Kreal = 256; Nn = 256; id = idx - 40960; }
    else if (idx < 172032) { W = w3;  D = w3p;  KT = 8; Kreal = 256; Nn = 256; id = idx - 106496; }
    else if (idx < 303104) { W = w4;  D = w4p;  KT = 8; Kreal = 256; Nn = 512; id = idx - 172032; }
    else if (idx < 335872) { W = wl0; D = wl0p; KT = 8; Kreal = 256; Nn = 128; id = idx - 303104; }
    else                   { W = wl1; D = wl1p; KT = 8; Kreal = 256; Nn = 128; id = idx - 335872; }
    int j = id & 7, lane = (id >> 3) & 63, tt = id >> 9;
    int kt = tt % KT, nt = tt / KT;
    int k = kt * 32 + ((lane >> 4) << 3) + j;
    int nn = nt * 16 + (lane & 15);
    D[id] = (k < Kreal) ? f2bf(W[k * Nn + nn]) : (ushort)0;
}

// ---------------------------------------------------------------------------
// Node up/down projections. u1 stored PLANAR: u1[n*384 + i*128 + v].
// ---------------------------------------------------------------------------
__global__ __launch_bounds__(256) void node_uud_kernel(
    const float* __restrict__ nf,
    const float* __restrict__ Wu0, const float* __restrict__ Wu1,
    const float* __restrict__ Wd,
    ushort* __restrict__ u0, ushort* __restrict__ u1,
    ushort* __restrict__ down)
{
    __shared__ float x[512];
    int n = blockIdx.x, t = threadIdx.x;
    for (int i = t; i < 512; i += 256) x[i] = nf[(size_t)n * 512 + i];
    __syncthreads();
    int v = t & 127;
    if (t < 128) {
        float acc = 0.f;
        for (int u = 0; u < 128; ++u) acc += x[u] * Wu0[u * 128 + v];
        u0[(size_t)n * 128 + v] = f2bf(acc * INV_C);
        if (t < 64) {
            float a3 = 0.f;
            for (int u = 0; u < 128; ++u) a3 += x[u] * Wd[u * 64 + t];
            down[(size_t)n * 64 + t] = f2bf(a3 * INV_C);
        }
    } else {
        for (int i = 0; i < 3; ++i) {
            float a2 = 0.f;
            for (int u = 0; u < 128; ++u) a2 += x[128 + u * 3 + i] * Wu1[u * 128 + v];
            u1[(size_t)n * 384 + i * 128 + v] = f2bf(a2 * INV_C);   // planar
        }
    }
}

// ---------------------------------------------------------------------------
// Skip connection (runs LAST — overwrites scratch with fp32 sc output).
// ---------------------------------------------------------------------------
__global__ __launch_bounds__(256) void node_sc_kernel(
    const float* __restrict__ nf,
    const float* __restrict__ Ws0, const float* __restrict__ Ws1,
    float* __restrict__ out_sc)
{
    __shared__ float x[512];
    int n = blockIdx.x, t = threadIdx.x;
    for (int i = t; i < 512; i += 256) x[i] = nf[(size_t)n * 512 + i];
    __syncthreads();
    int v = t & 127;
    if (t < 128) {
        float acc = 0.f;
        for (int u = 0; u < 128; ++u) acc += x[u] * Ws0[u * 128 + v];
        out_sc[(size_t)n * 512 + v] = fin(acc * INV_C);
    } else {
        for (int i = 0; i < 3; ++i) {
            float a2 = 0.f;
            for (int u = 0; u < 128; ++u) a2 += x[128 + u * 3 + i] * Ws1[u * 128 + v];
            out_sc[(size_t)n * 512 + 128 + v * 3 + i] = fin(a2 * INV_C);
        }
    }
}

// ---------------------------------------------------------------------------
// CSR build (receiver-sorted edge list) — path A only.
// ---------------------------------------------------------------------------
__global__ __launch_bounds__(256) void hist_kernel(const int* __restrict__ eidx, int* __restrict__ counts)
{
    int e = blockIdx.x * 256 + threadIdx.x;
    int r = eidx[N_EDGES + e];
    if (r < 0) r = 0; if (r >= N_NODES) r = N_NODES - 1;
    atomicAdd(&counts[r], 1);
}

__global__ __launch_bounds__(1024) void scan_kernel(const int* __restrict__ counts, int* __restrict__ offs)
{
    __shared__ int buf[1024];
    __shared__ int base_s;
    int t = threadIdx.x;
    if (t == 0) { base_s = 0; offs[0] = 0; }
    __syncthreads();
    for (int chunk = 0; chunk < (N_NODES + 1023) / 1024; ++chunk) {
        int i = chunk * 1024 + t;
        int vv = (i < N_NODES) ? counts[i] : 0;
        buf[t] = vv;
        __syncthreads();
        for (int off = 1; off < 1024; off <<= 1) {
            int xv = (t >= off) ? buf[t - off] : 0;
            __syncthreads();
            buf[t] += xv;
            __syncthreads();
        }
        int incl = buf[t];
        int base = base_s;
        __syncthreads();
        if (i < N_NODES) offs[i + 1] = base + incl;
        if (t == 1023) base_s = base + incl;
        __syncthreads();
    }
}

__global__ __launch_bounds__(256) void fill_kernel(
    const int* __restrict__ eidx, const int* __restrict__ offs,
    int* __restrict__ cnt2, int* __restrict__ esort)
{
    int e = blockIdx.x * 256 + threadIdx.x;
    int r = eidx[N_EDGES + e];
    if (r < 0) r = 0; if (r >= N_NODES) r = N_NODES - 1;
    int k = atomicAdd(&cnt2[r], 1);
    int pos = offs[r] + k;
    if (pos < 0) pos = 0; if (pos >= N_EDGES) pos = N_EDGES - 1;
    esort[pos] = e;
}

// ---------------------------------------------------------------------------
// Hidden-layer MFMA GEMM: 32 edges x 256 out, bf16 LDS->LDS.
// A-frag: lane l holds A[m=l&15][k=(l>>4)*8+j]; C/D: row=(l>>4)*4+r, col=l&15.
// ---------------------------------------------------------------------------
#define H_STRIDE 264

template <int KT, bool SILU>
__device__ __forceinline__ void gemm_layer(
    const ushort* __restrict__ wpack, const ushort* srcLDS, int srcStride,
    ushort* dstLDS, float scale)
{
    int t = threadIdx.x;
    int w = t >> 6, l = t & 63;
    int mt = w & 1;
    int ntbase = (w >> 1) * 8;
    int lrow = l & 15, q = l >> 4;

    v8s a[KT];
#pragma unroll
    for (int kt = 0; kt < KT; ++kt)
        a[kt] = *(const v8s*)&srcLDS[(mt * 16 + lrow) * srcStride + kt * 32 + q * 8];

    for (int p = 0; p < 4; ++p) {
        int nt0 = ntbase + 2 * p, nt1 = nt0 + 1;
        v4f acc0 = {0.f, 0.f, 0.f, 0.f}, acc1 = {0.f, 0.f, 0.f, 0.f};
#pragma unroll
        for (int kt = 0; kt < KT; ++kt) {
            v8s b0 = *(const v8s*)&wpack[(size_t)(nt0 * KT + kt) * 512 + l * 8];
            v8s b1 = *(const v8s*)&wpack[(size_t)(nt1 * KT + kt) * 512 + l * 8];
            acc0 = __builtin_amdgcn_mfma_f32_16x16x32_bf16(a[kt], b0, acc0, 0, 0, 0);
            acc1 = __builtin_amdgcn_mfma_f32_16x16x32_bf16(a[kt], b1, acc1, 0, 0, 0);
        }
#pragma unroll
        for (int r = 0; r < 4; ++r) {
            float x0 = acc0[r] * scale, x1 = acc1[r] * scale;
            if (SILU) {
                x0 = x0 / (1.f + __expf(-x0));
                x1 = x1 / (1.f + __expf(-x1));
            }
            int row = mt * 16 + q * 4 + r;
            dstLDS[row * H_STRIDE + nt0 * 16 + lrow] = f2bf(x0);
            dstLDS[row * H_STRIDE + nt1 * 16 + lrow] = f2bf(x1);
        }
    }
    __syncthreads();
}

// GEMM [32x256]@[256x128]; path B: atomicAdd into out_msg (interleaved);
// path A: bf16 store into PLANAR tpw[cofs][E][128] (coalesced 32B segments).
template <bool ATOMIC>
__device__ __forceinline__ void gemm_out(
    const ushort* __restrict__ wpack, const ushort* srcLDS,
    const int* s_rcv, float* __restrict__ out, ushort* __restrict__ tpw,
    int e0, int cofs)
{
    int t = threadIdx.x;
    int w = t >> 6, l = t & 63;
    int mt = w & 1;
    int ntbase = (w >> 1) * 4;
    int lrow = l & 15, q = l >> 4;
    v8s a[8];
#pragma unroll
    for (int kt = 0; kt < 8; ++kt)
        a[kt] = *(const v8s*)&srcLDS[(mt * 16 + lrow) * H_STRIDE + kt * 32 + q * 8];
    ushort* plane = tpw + (size_t)cofs * TPW_PLANE;
#pragma unroll
    for (int pp = 0; pp < 2; ++pp) {
        int nt0 = ntbase + 2 * pp, nt1 = nt0 + 1;
        v4f acc0 = {0.f, 0.f, 0.f, 0.f}, acc1 = {0.f, 0.f, 0.f, 0.f};
#pragma unroll
        for (int kt = 0; kt < 8; ++kt) {
            v8s b0 = *(const v8s*)&wpack[(size_t)(nt0 * 8 + kt) * 512 + l * 8];
            v8s b1 = *(const v8s*)&wpack[(size_t)(nt1 * 8 + kt) * 512 + l * 8];
            acc0 = __builtin_amdgcn_mfma_f32_16x16x32_bf16(a[kt], b0, acc0, 0, 0, 0);
            acc1 = __builtin_amdgcn_mfma_f32_16x16x32_bf16(a[kt], b1, acc1, 0, 0, 0);
        }
        int col0 = nt0 * 16 + lrow, col1 = nt1 * 16 + lrow;
#pragma unroll
        for (int r = 0; r < 4; ++r) {
            int row = mt * 16 + q * 4 + r;
            if constexpr (ATOMIC) {
                int rcv = s_rcv[row];
                atomicAdd(&out[(size_t)rcv * 512 + col0 * 4 + cofs], fin(acc0[r] * OUT_SCALE));
                atomicAdd(&out[(size_t)rcv * 512 + col1 * 4 + cofs], fin(acc1[r] * OUT_SCALE));
            } else {
                size_t base = (size_t)(e0 + row) * 128;
                plane[base + col0] = f2bf(acc0[r] * OUT_SCALE);
                plane[base + col1] = f2bf(acc1[r] * OUT_SCALE);
            }
        }
    }
}

// ---------------------------------------------------------------------------
// Edge-parallel fused kernel: 32 edges/block.
// ---------------------------------------------------------------------------
template <bool ATOMIC>
__global__ __launch_bounds__(256, 2) void edge_msg_kernel(
    const int* __restrict__ eidx,
    const float* __restrict__ ef, const float* __restrict__ ea,
    const ushort* __restrict__ down,
    const ushort* __restrict__ u0, const ushort* __restrict__ u1,
    const ushort* __restrict__ w1p, const ushort* __restrict__ w2p,
    const ushort* __restrict__ w3p, const ushort* __restrict__ w4p,
    const ushort* __restrict__ wl0p, const ushort* __restrict__ wl1p,
    float* __restrict__ out_msg, ushort* __restrict__ tpw)
{
    __shared__ __align__(16) ushort s_aug[32 * 168];
    __shared__ __align__(16) ushort s_hA[32 * H_STRIDE];
    __shared__ __align__(16) ushort s_hB[32 * H_STRIDE];
    __shared__ __align__(16) ushort s_q1[32 * 136];
    __shared__ __align__(16) ushort s_q2[32 * 136];
    __shared__ int s_snd[32];
    __shared__ int s_rcv[32];
    __shared__ float s_y[32][4];

    int t = threadIdx.x;
    int e0 = blockIdx.x * 32;

    if (t < 32) {
        int e = e0 + t;
        int s = eidx[e];
        int r = eidx[N_EDGES + e];
        if (s < 0) s = 0; if (s >= N_NODES) s = N_NODES - 1;
        if (r < 0) r = 0; if (r >= N_NODES) r = N_NODES - 1;
        s_snd[t] = s; s_rcv[t] = r;
        s_y[t][0] = fin(ea[(size_t)e * 4 + 0]);
        s_y[t][1] = fin(ea[(size_t)e * 4 + 1]);
        s_y[t][2] = fin(ea[(size_t)e * 4 + 2]);
        s_y[t][3] = fin(ea[(size_t)e * 4 + 3]);
    }
    __syncthreads();
    for (int i = t; i < 32 * 168; i += 256) {
        int e = i / 168, cc = i - e * 168;
        ushort vv = 0;
        if (cc < 8)        vv = f2bf(ef[(size_t)(e0 + e) * 8 + cc]);
        else if (cc < 72)  vv = down[(size_t)s_snd[e] * 64 + (cc - 8)];
        else if (cc < 136) vv = down[(size_t)s_rcv[e] * 64 + (cc - 72)];
        s_aug[i] = vv;
    }
    __syncthreads();
    gemm_layer<5, true>(w1p, s_aug, 168, s_hA, S_MLP1);
    gemm_layer<8, true>(w2p, s_hA, H_STRIDE, s_hB, S_MLP);
    gemm_layer<8, true>(w3p, s_hB, H_STRIDE, s_hA, S_MLP);

    // ---- layer 4 quarters, contracted in-register ----
    int w = t >> 6, l = t & 63;
    int mt = w & 1;
    int lrow = l & 15, q = l >> 4;
    v8s a4[8];
#pragma unroll
    for (int kt = 0; kt < 8; ++kt)
        a4[kt] = *(const v8s*)&s_hA[(mt * 16 + lrow) * H_STRIDE + kt * 32 + q * 8];

    for (int qd = 0; qd < 4; ++qd) {
#pragma unroll
        for (int pp = 0; pp < 2; ++pp) {
            int nt0 = qd * 8 + (w >> 1) * 4 + pp * 2;
            int nt1 = nt0 + 1;
            v4f acc0 = {0.f, 0.f, 0.f, 0.f}, acc1 = {0.f, 0.f, 0.f, 0.f};
#pragma unroll
            for (int kt = 0; kt < 8; ++kt) {
                v8s b0 = *(const v8s*)&w4p[(size_t)(nt0 * 8 + kt) * 512 + l * 8];
                v8s b1 = *(const v8s*)&w4p[(size_t)(nt1 * 8 + kt) * 512 + l * 8];
                acc0 = __builtin_amdgcn_mfma_f32_16x16x32_bf16(a4[kt], b0, acc0, 0, 0, 0);
                acc1 = __builtin_amdgcn_mfma_f32_16x16x32_bf16(a4[kt], b1, acc1, 0, 0, 0);
            }
            int col0 = (nt0 * 16 + lrow) & 127;
            int col1 = col0 + 16;
#pragma unroll
            for (int r = 0; r < 4; ++r) {
                int row = mt * 16 + q * 4 + r;
                int snd = s_snd[row];
                float v0 = acc0[r] * S_MLP, v1 = acc1[r] * S_MLP;
                if (qd == 0) {
                    float y0 = s_y[row][0];
                    s_hB[row * H_STRIDE + col0] =
                        f2bf(v0 * bf2f(u0[(size_t)snd * 128 + col0]) * y0);
                    s_hB[row * H_STRIDE + col1] =
                        f2bf(v1 * bf2f(u0[(size_t)snd * 128 + col1]) * y0);
                } else if (qd == 1) {
                    s_q1[row * 136 + col0] = f2bf(v0 * bf2f(u0[(size_t)snd * 128 + col0]));
                    s_q1[row * 136 + col1] = f2bf(v1 * bf2f(u0[(size_t)snd * 128 + col1]));
                } else if (qd == 2) {
                    s_q2[row * 136 + col0] = f2bf(v0);
                    s_q2[row * 136 + col1] = f2bf(v1);
                } else {
                    // u1 planar: [snd][i][128]
                    size_t ub = (size_t)snd * 384;
                    float d0 = bf2f(u1[ub + col0])       * s_y[row][1]
                             + bf2f(u1[ub + 128 + col0]) * s_y[row][2]
                             + bf2f(u1[ub + 256 + col0]) * s_y[row][3];
                    float d1 = bf2f(u1[ub + col1])       * s_y[row][1]
                             + bf2f(u1[ub + 128 + col1]) * s_y[row][2]
                             + bf2f(u1[ub + 256 + col1]) * s_y[row][3];
                    s_hB[row * H_STRIDE + 128 + col0] = f2bf(v0 * d0 * INV_SQRT3);
                    s_hB[row * H_STRIDE + 128 + col1] = f2bf(v1 * d1 * INV_SQRT3);
                }
            }
        }
    }
    __syncthreads();

    gemm_out<ATOMIC>(wl0p, s_hB, s_rcv, out_msg, tpw, e0, 0);
    __syncthreads();

    for (int i = 0; i < 3; ++i) {
        for (int idx = t; idx < 32 * 256; idx += 256) {
            int e = idx >> 8, c = idx & 255;
            float val;
            if (c < 128) {
                val = bf2f(s_q1[e * 136 + c]) * s_y[e][1 + i];
            } else {
                int cc = c - 128;
                val = bf2f(s_q2[e * 136 + cc])
                    * bf2f(u1[(size_t)s_snd[e] * 384 + i * 128 + cc]) * s_y[e][0];
            }
            s_hA[e * H_STRIDE + c] = f2bf(val);
        }
        __syncthreads();
        gemm_out<ATOMIC>(wl1p, s_hA, s_rcv, out_msg, tpw, e0, 1 + i);
        __syncthreads();
    }
}

// ---------------------------------------------------------------------------
// Path A gather: out_msg[n][col*4+cofs] = sum over n's edges of tpw[cofs][e][col].
// ---------------------------------------------------------------------------
__global__ __launch_bounds__(256) void gather_kernel(
    const int* __restrict__ offs, const int* __restrict__ esort,
    const ushort* __restrict__ tpw, float* __restrict__ out_msg)
{
    int n = blockIdx.x, t = threadIdx.x;
    int beg = offs[n];
    if (beg < 0) beg = 0; if (beg > N_EDGES) beg = N_EDGES;
    int end = offs[n + 1];
    if (end < beg) end = beg; if (end > N_EDGES) end = N_EDGES;
    int col = t & 127, ca = t >> 7, cb = ca + 2;
    const ushort* pA = tpw + (size_t)ca * TPW_PLANE + col;
    const ushort* pB = tpw + (size_t)cb * TPW_PLANE + col;
    float a0 = 0.f, a1 = 0.f;
    for (int j = beg; j < end; ++j) {
        int e = esort[j];
        if (e < 0) e = 0; if (e >= N_EDGES) e = N_EDGES - 1;
        a0 += bf2f(pA[(size_t)e * 128]);
        a1 += bf2f(pB[(size_t)e * 128]);
    }
    out_msg[(size_t)n * 512 + col * 4 + ca] = fin(a0);
    out_msg[(size_t)n * 512 + col * 4 + cb] = fin(a1);
}

// ---------------------------------------------------------------------------
extern "C" void kernel_launch(void* const* d_in, const int* in_sizes, int n_in,
                              void* d_out, int out_size, void* d_ws, size_t ws_size,
                              hipStream_t stream)
{
    const float* node_feats = (const float*)d_in[1];
    const float* edge_attrs = (const float*)d_in[2];
    const float* edge_feats = (const float*)d_in[3];
    const int*   edge_index = (const int*)d_in[4];
    const float* W_up0  = (const float*)d_in[5];
    const float* W_up1  = (const float*)d_in[6];
    const float* W_down = (const float*)d_in[7];
    const float* mlp_w1 = (const float*)d_in[8];
    const float* mlp_w2 = (const float*)d_in[9];
    const float* mlp_w3 = (const float*)d_in[10];
    const float* mlp_w4 = (const float*)d_in[11];
    const float* W_lin0 = (const float*)d_in[12];
    const float* W_lin1 = (const float*)d_in[13];
    const float* W_skip0 = (const float*)d_in[14];
    const float* W_skip1 = (const float*)d_in[15];

    // d_out fp32: [message: 20,480,000 B][sc: 20,480,000 B]
    char* S = (char*)d_out + 20480000;   // sc half = scratch until node_sc

    ushort* u0    = (ushort*)(S + 0);           //  2,560,000 B
    ushort* down  = (ushort*)(S + 2560000);     //  1,280,000 B
    ushort* u1    = (ushort*)(S + 3840000);     //  7,680,000 B (planar [n][i][128])
    ushort* w1p   = (ushort*)(S + 11520000);    //     81,920 B
    ushort* w2p   = (ushort*)(S + 11601920);    //    131,072 B
    ushort* w3p   = (ushort*)(S + 11732992);    //    131,072 B
    ushort* w4p   = (ushort*)(S + 11864064);    //    262,144 B
    ushort* wl0p  = (ushort*)(S + 12126208);    //     65,536 B
    ushort* wl1p  = (ushort*)(S + 12191744);    //     65,536 B
    int*    offs  = (int*)(S + 12257280);       //     40,032 B
    int*    esort = (int*)(S + 12297312);       //    640,000 B
    int*    counts= (int*)(S + 12937312);       //     40,000 B
    int*    cnt2  = (int*)(S + 12977312);       //     40,000 B -> 13,017,312

    float* out_msg = (float*)d_out;
    float* out_sc  = (float*)d_out + (size_t)N_NODES * 512;

    const size_t TPW_BYTES = (size_t)N_EDGES * 512 * 2;   // 163,840,000
    bool bigws = (ws_size >= TPW_BYTES) && (d_ws != nullptr);
    ushort* tpw = (ushort*)d_ws;

    pack_kernel<<<1440, 256, 0, stream>>>(mlp_w1, mlp_w2, mlp_w3, mlp_w4, W_lin0, W_lin1,
                                          w1p, w2p, w3p, w4p, wl0p, wl1p);
    node_uud_kernel<<<N_NODES, 256, 0, stream>>>(node_feats, W_up0, W_up1, W_down, u0, u1, down);

    if (bigws) {
        hipMemsetAsync(counts, 0, 80000, stream);
        hist_kernel<<<N_EDGES / 256, 256, 0, stream>>>(edge_index, counts);
        scan_kernel<<<1, 1024, 0, stream>>>(counts, offs);
        fill_kernel<<<N_EDGES / 256, 256, 0, stream>>>(edge_index, offs, cnt2, esort);
        edge_msg_kernel<false><<<N_EDGES / 32, 256, 0, stream>>>(edge_index, edge_feats, edge_attrs,
            down, u0, u1, w1p, w2p, w3p, w4p, wl0p, wl1p, out_msg, tpw);
        gather_kernel<<<N_NODES, 256, 0, stream>>>(offs, esort, tpw, out_msg);
    } else {
        hipMemsetAsync(out_msg, 0, 20480000, stream);
        edge_msg_kernel<true><<<N_EDGES / 32, 256, 0, stream>>>(edge_index, edge_feats, edge_attrs,
            down, u0, u1, w1p, w2p, w3p, w4p, wl0p, wl1p, out_msg, tpw);
    }
    node_sc_kernel<<<N_NODES, 256, 0, stream>>>(node_feats, W_skip0, W_skip1, out_sc);
}